// Round 9
// baseline (109.023 us; speedup 1.0000x reference)
//
#include <hip/hip_runtime.h>

#define L_TOK   2048
#define N_FRAMES 8192
#define C_D     640
#define C_T     512
#define N_ROWS  (C_D + C_T)   // 1152

// Kernel 1: prefix-scan durations, build frame -> token map in workspace.
// Single block of 1024 threads; each thread owns 2 consecutive tokens.
__global__ __launch_bounds__(1024) void build_tokmap_kernel(
    const int* __restrict__ pred_dur, int* __restrict__ tokmap) {
    __shared__ int part[1024];
    const int t = threadIdx.x;

    // Fill the whole map with -1 (frames past total stay "no token").
    // d_ws is re-poisoned before every launch, so this must happen every call.
    #pragma unroll
    for (int i = 0; i < N_FRAMES / 1024; ++i)
        tokmap[t + i * 1024] = -1;

    // Each thread loads its 2 durations.
    const int d0 = pred_dur[2 * t];
    const int d1 = pred_dur[2 * t + 1];
    const int local = d0 + d1;
    part[t] = local;
    __syncthreads();   // also orders the -1 global fill before the scatter below

    // Hillis-Steele inclusive scan over the 1024 per-thread partial sums.
    for (int off = 1; off < 1024; off <<= 1) {
        int v = (t >= off) ? part[t - off] : 0;
        __syncthreads();
        part[t] += v;
        __syncthreads();
    }

    // Exclusive prefix for this thread's first token.
    const int excl = part[t] - local;

    // Scatter token ids over their frame ranges (dur in [0,4], <=8 writes).
    const int tok0 = 2 * t;
    for (int k = 0; k < d0; ++k) tokmap[excl + k] = tok0;
    const int s1 = excl + d0;
    for (int k = 0; k < d1; ++k) tokmap[s1 + k] = tok0 + 1;
}

// Kernel 2: gather. Flat output layout is [1152 rows][8192 frames], f fastest.
// Row r < 640:  out[r][f] = d[tok(f)*640 + r]        (en)
// Row r >= 640: out[r][f] = t_en[(r-640)*2048 + tok(f)]  (asr)
// Each thread produces 4 consecutive frames (float4 write).
__global__ __launch_bounds__(256) void gather_kernel(
    const float* __restrict__ d, const float* __restrict__ t_en,
    const int* __restrict__ tokmap, float* __restrict__ out) {
    const int gid = blockIdx.x * 256 + threadIdx.x;
    const int groups_per_row = N_FRAMES / 4;          // 2048
    const int f = (gid & (groups_per_row - 1)) * 4;   // frame base
    const int row = gid >> 11;                        // gid / 2048
    if (row >= N_ROWS) return;

    const int4 tok = *reinterpret_cast<const int4*>(tokmap + f);

    float4 v;
    if (row < C_D) {
        v.x = (tok.x < 0) ? 0.0f : d[(size_t)tok.x * C_D + row];
        v.y = (tok.y < 0) ? 0.0f : d[(size_t)tok.y * C_D + row];
        v.z = (tok.z < 0) ? 0.0f : d[(size_t)tok.z * C_D + row];
        v.w = (tok.w < 0) ? 0.0f : d[(size_t)tok.w * C_D + row];
    } else {
        const float* src = t_en + (size_t)(row - C_D) * L_TOK;
        v.x = (tok.x < 0) ? 0.0f : src[tok.x];
        v.y = (tok.y < 0) ? 0.0f : src[tok.y];
        v.z = (tok.z < 0) ? 0.0f : src[tok.z];
        v.w = (tok.w < 0) ? 0.0f : src[tok.w];
    }

    *reinterpret_cast<float4*>(out + (size_t)row * N_FRAMES + f) = v;
}

extern "C" void kernel_launch(void* const* d_in, const int* in_sizes, int n_in,
                              void* d_out, int out_size, void* d_ws, size_t ws_size,
                              hipStream_t stream) {
    const int*   pred_dur = (const int*)d_in[0];
    const float* d        = (const float*)d_in[1];
    const float* t_en     = (const float*)d_in[2];
    float* out = (float*)d_out;
    int*   tokmap = (int*)d_ws;   // 8192 ints = 32 KB

    build_tokmap_kernel<<<1, 1024, 0, stream>>>(pred_dur, tokmap);

    const int total_threads = N_ROWS * (N_FRAMES / 4);  // 1152 * 2048
    const int blocks = (total_threads + 255) / 256;     // 9216
    gather_kernel<<<blocks, 256, 0, stream>>>(d, t_en, tokmap, out);
}

// Round 12
// 85.824 us; speedup vs baseline: 1.2703x; 1.2703x over previous
//
#include <hip/hip_runtime.h>

#define L_TOK    2048
#define N_FRAMES 8192
#define C_D      640
#define C_T      512
#define N_ROWS   (C_D + C_T)   // 1152

// ws layout: [0, 32KB)  tokmap (8192 int32)
//            [32KB, +5.24MB) dT = d transposed to [640][2048]
#define TOKMAP_BYTES 32768

// Kernel 1 (combined): block 0 builds the frame->token map; blocks 1..1280
// transpose d[2048][640] -> dT[640][2048] in 32x32 LDS tiles.
__global__ __launch_bounds__(1024) void prep_kernel(
    const int* __restrict__ pred_dur, const float* __restrict__ d,
    int* __restrict__ tokmap, float* __restrict__ dT) {
    const int t = threadIdx.x;

    if (blockIdx.x == 0) {
        // ---- frame -> token map (prefix scan + scatter) ----
        __shared__ int part[1024];
        // Fill map with -1 (ws is re-poisoned every launch; must redo).
        #pragma unroll
        for (int i = 0; i < N_FRAMES / 1024; ++i)
            tokmap[t + i * 1024] = -1;

        const int d0 = pred_dur[2 * t];
        const int d1 = pred_dur[2 * t + 1];
        const int local = d0 + d1;
        part[t] = local;
        __syncthreads();   // also orders the -1 fill before the scatter

        for (int off = 1; off < 1024; off <<= 1) {
            int v = (t >= off) ? part[t - off] : 0;
            __syncthreads();
            part[t] += v;
            __syncthreads();
        }
        const int excl = part[t] - local;   // exclusive prefix

        const int tok0 = 2 * t;
        for (int k = 0; k < d0; ++k) tokmap[excl + k] = tok0;
        const int s1 = excl + d0;
        for (int k = 0; k < d1; ++k) tokmap[s1 + k] = tok0 + 1;
    } else {
        // ---- 32x32 tile transpose of d ----
        __shared__ float tile[32][33];      // +1 pad: conflict-free both ways
        const int bid = blockIdx.x - 1;     // 0 .. 64*20-1
        const int by = bid / (C_D / 32);    // token tile (0..63)
        const int bx = bid % (C_D / 32);    // channel tile (0..19)
        const int tx = t & 31;
        const int ty = t >> 5;              // 0..31 (1024 threads = full tile)

        // read: consecutive tx -> consecutive channels (coalesced)
        tile[ty][tx] = d[(size_t)(by * 32 + ty) * C_D + (bx * 32 + tx)];
        __syncthreads();
        // write: consecutive tx -> consecutive tokens (coalesced)
        dT[(size_t)(bx * 32 + ty) * L_TOK + (by * 32 + tx)] = tile[tx][ty];
    }
}

// Kernel 2: uniform gather. out[r][f] = src_r[tok(f)] (0 if tok<0), where
// src_r = dT+r*2048 for r<640 (en), t_en+(r-640)*2048 for r>=640 (asr).
// Lane-consecutive f -> near-consecutive tok -> near-coalesced reads.
__global__ __launch_bounds__(256) void gather_kernel(
    const float* __restrict__ dT, const float* __restrict__ t_en,
    const int* __restrict__ tokmap, float* __restrict__ out) {
    const int gid = blockIdx.x * 256 + threadIdx.x;
    const int f = (gid & (N_FRAMES / 4 - 1)) * 4;   // frame base (x4)
    const int row = gid >> 11;                       // gid / 2048
    if (row >= N_ROWS) return;

    const int4 tok = *reinterpret_cast<const int4*>(tokmap + f);
    const float* __restrict__ src = (row < C_D)
        ? dT + (size_t)row * L_TOK
        : t_en + (size_t)(row - C_D) * L_TOK;

    float4 v;
    v.x = (tok.x < 0) ? 0.0f : src[tok.x];
    v.y = (tok.y < 0) ? 0.0f : src[tok.y];
    v.z = (tok.z < 0) ? 0.0f : src[tok.z];
    v.w = (tok.w < 0) ? 0.0f : src[tok.w];

    *reinterpret_cast<float4*>(out + (size_t)row * N_FRAMES + f) = v;
}

extern "C" void kernel_launch(void* const* d_in, const int* in_sizes, int n_in,
                              void* d_out, int out_size, void* d_ws, size_t ws_size,
                              hipStream_t stream) {
    const int*   pred_dur = (const int*)d_in[0];
    const float* d        = (const float*)d_in[1];
    const float* t_en     = (const float*)d_in[2];
    float* out    = (float*)d_out;
    int*   tokmap = (int*)d_ws;
    float* dT     = (float*)((char*)d_ws + TOKMAP_BYTES);

    // 1 scan block + 64*20 transpose blocks
    prep_kernel<<<1 + (L_TOK / 32) * (C_D / 32), 1024, 0, stream>>>(
        pred_dur, d, tokmap, dT);

    const int total_threads = N_ROWS * (N_FRAMES / 4);  // 1152 * 2048
    gather_kernel<<<(total_threads + 255) / 256, 256, 0, stream>>>(
        dT, t_en, tokmap, out);
}

// Round 13
// 84.820 us; speedup vs baseline: 1.2853x; 1.0118x over previous
//
#include <hip/hip_runtime.h>

#define L_TOK    2048
#define N_FRAMES 8192
#define C_D      640
#define C_T      512
#define FT       256                 // frames per block
#define RT       32                  // rows per block
#define N_FT     (N_FRAMES / FT)     // 32 frame tiles
#define N_RT_EN  (C_D / RT)          // 20 en row-tiles
#define N_RT_ASR (C_T / RT)          // 16 asr row-tiles

// One fused kernel: per-block redundant duration scan -> frame->token map in
// LDS -> gather/write one [32 rows x 256 frames] output tile.
// Reads only pristine inputs (clean cache lines; no cross-XCD dirty-L2 path),
// uses no workspace, single launch.
__global__ __launch_bounds__(256) void fused_align_kernel(
    const int* __restrict__ pred_dur, const float* __restrict__ d,
    const float* __restrict__ t_en, float* __restrict__ out) {

    __shared__ int   fmap[FT];          // frame -> token id (-1 = none)
    __shared__ int   ssum[256];         // scan partials
    __shared__ float ldo[RT][FT + 4];   // en staging tile, row stride 260 (16B-aligned, padded)

    const int t     = threadIdx.x;
    const int bid   = blockIdx.x;
    const int ftile = bid % N_FT;
    const int rtile = bid / N_FT;       // 0..35
    const int f0    = ftile * FT;

    // ---- Phase A: redundant global scan + window frame-map ----
    fmap[t] = -1;

    // 8 tokens per thread (2048 / 256), vector loads
    const int4 da = ((const int4*)pred_dur)[t * 2];
    const int4 db = ((const int4*)pred_dur)[t * 2 + 1];
    int dur[8] = {da.x, da.y, da.z, da.w, db.x, db.y, db.z, db.w};
    int pre[8];
    int lsum = 0;
    #pragma unroll
    for (int k = 0; k < 8; ++k) { pre[k] = lsum; lsum += dur[k]; }
    ssum[t] = lsum;
    __syncthreads();                    // orders fmap init + ssum stores

    #pragma unroll
    for (int off = 1; off < 256; off <<= 1) {   // Hillis-Steele, 8 rounds
        int v = (t >= off) ? ssum[t - off] : 0;
        __syncthreads();
        ssum[t] += v;
        __syncthreads();
    }
    const int excl = ssum[t] - lsum;    // exclusive prefix of this thread's 8 tokens

    #pragma unroll
    for (int k = 0; k < 8; ++k) {       // scatter token ids into this window
        const int s  = excl + pre[k];
        const int e  = s + dur[k];
        const int lo = s < f0 ? f0 : s;
        const int hi = e > f0 + FT ? f0 + FT : e;
        for (int f = lo; f < hi; ++f) fmap[f - f0] = t * 8 + k;
    }
    __syncthreads();

    // ---- Phase B: produce one 32x256 output tile ----
    if (rtile < N_RT_EN) {
        // en rows: out[r][f] = d[tok(f)][r]. Stage d rows (clean lines,
        // float4-coalesced) into ldo[r_local][f_local], then write coalesced.
        const int r0 = rtile * RT;
        const int q  = t & 7;           // channel quarter (4 floats)
        const int fl = t >> 3;          // frame sub-index (0..31)
        #pragma unroll
        for (int i = 0; i < 8; ++i) {
            const int f_local = fl + i * 32;
            const int tok = fmap[f_local];
            float4 v = make_float4(0.f, 0.f, 0.f, 0.f);
            if (tok >= 0)
                v = *(const float4*)&d[(size_t)tok * C_D + r0 + q * 4];
            ldo[q * 4 + 0][f_local] = v.x;
            ldo[q * 4 + 1][f_local] = v.y;
            ldo[q * 4 + 2][f_local] = v.z;
            ldo[q * 4 + 3][f_local] = v.w;
        }
        __syncthreads();
        const int lane4 = t & 63;       // frame group within row
        const int wid   = t >> 6;       // 0..3
        #pragma unroll
        for (int i = 0; i < 8; ++i) {
            const int row = i * 4 + wid;
            const float4 v = *(const float4*)&ldo[row][lane4 * 4];
            *(float4*)&out[(size_t)(r0 + row) * N_FRAMES + f0 + lane4 * 4] = v;
        }
    } else {
        // asr rows: out[640+r][f] = t_en[r][tok(f)] — row-contiguous gather.
        const int r0 = (rtile - N_RT_EN) * RT;
        const int lane4 = t & 63;
        const int wid   = t >> 6;
        #pragma unroll
        for (int i = 0; i < 8; ++i) {
            const int row = i * 4 + wid;
            const float* __restrict__ src = t_en + (size_t)(r0 + row) * L_TOK;
            const int fb = lane4 * 4;
            float4 v;
            const int t0 = fmap[fb + 0], t1 = fmap[fb + 1];
            const int t2 = fmap[fb + 2], t3 = fmap[fb + 3];
            v.x = (t0 < 0) ? 0.f : src[t0];
            v.y = (t1 < 0) ? 0.f : src[t1];
            v.z = (t2 < 0) ? 0.f : src[t2];
            v.w = (t3 < 0) ? 0.f : src[t3];
            *(float4*)&out[(size_t)(C_D + r0 + row) * N_FRAMES + f0 + fb] = v;
        }
    }
}

extern "C" void kernel_launch(void* const* d_in, const int* in_sizes, int n_in,
                              void* d_out, int out_size, void* d_ws, size_t ws_size,
                              hipStream_t stream) {
    const int*   pred_dur = (const int*)d_in[0];
    const float* d        = (const float*)d_in[1];
    const float* t_en     = (const float*)d_in[2];
    float* out = (float*)d_out;

    const int blocks = (N_RT_EN + N_RT_ASR) * N_FT;   // 36 * 32 = 1152
    fused_align_kernel<<<blocks, 256, 0, stream>>>(pred_dur, d, t_en, out);
}

// Round 17
// 83.298 us; speedup vs baseline: 1.3088x; 1.0183x over previous
//
#include <hip/hip_runtime.h>

#define L_TOK    2048
#define N_FRAMES 8192
#define C_D      640
#define C_T      512
#define FT       256                 // frames per block
#define RT       32                  // rows per block
#define N_FT     (N_FRAMES / FT)     // 32 frame tiles
#define N_RT_EN  (C_D / RT)          // 20 en row-tiles
#define N_RT_ASR (C_T / RT)          // 16 asr row-tiles

// One fused kernel: per-block redundant duration scan (wave-shuffle based,
// 2 barriers total) -> frame->token map in LDS -> one [32 x 256] output tile.
// Reads only pristine inputs, no workspace, single launch.
__global__ __launch_bounds__(256) void fused_align_kernel(
    const int* __restrict__ pred_dur, const float* __restrict__ d,
    const float* __restrict__ t_en, float* __restrict__ out) {

    __shared__ int   fmap[FT];          // frame -> token id (-1 = none)
    __shared__ int   wsum[4];           // per-wave totals
    __shared__ float ldo[RT][FT + 4];   // en staging tile (row stride 260)

    const int t     = threadIdx.x;
    const int bid   = blockIdx.x;
    const int ftile = bid % N_FT;
    const int rtile = bid / N_FT;       // 0..35
    const int f0    = ftile * FT;

    // ---- Phase A: scan + window frame-map (2 barriers) ----
    fmap[t] = -1;

    // 8 tokens per thread, vector loads
    const int4 da = ((const int4*)pred_dur)[t * 2];
    const int4 db = ((const int4*)pred_dur)[t * 2 + 1];
    int dur[8] = {da.x, da.y, da.z, da.w, db.x, db.y, db.z, db.w};
    int pre[8];
    int lsum = 0;
    #pragma unroll
    for (int k = 0; k < 8; ++k) { pre[k] = lsum; lsum += dur[k]; }

    // intra-wave inclusive scan of lsum (64 lanes, no barriers)
    int incl = lsum;
    #pragma unroll
    for (int off = 1; off < 64; off <<= 1) {
        int v = __shfl_up(incl, off, 64);
        if ((t & 63) >= off) incl += v;
    }
    if ((t & 63) == 63) wsum[t >> 6] = incl;
    __syncthreads();                    // orders fmap init + wsum stores

    int wpre = 0;
    #pragma unroll
    for (int w = 0; w < 4; ++w) wpre += (w < (t >> 6)) ? wsum[w] : 0;
    const int excl = wpre + incl - lsum;   // exclusive prefix, this thread's 8 tokens

    #pragma unroll
    for (int k = 0; k < 8; ++k) {       // scatter token ids into this window
        const int s  = excl + pre[k];
        const int e  = s + dur[k];
        const int lo = s < f0 ? f0 : s;
        const int hi = e > f0 + FT ? f0 + FT : e;
        for (int f = lo; f < hi; ++f) fmap[f - f0] = t * 8 + k;
    }
    __syncthreads();

    // ---- Phase B: produce one 32x256 output tile ----
    if (rtile < N_RT_EN) {
        // en rows: out[r][f] = d[tok(f)][r]. Stage float4 slices of d rows
        // into ldo (transpose in LDS), then write float4-coalesced.
        const int r0 = rtile * RT;
        const int q  = t & 7;           // channel quarter (4 floats)
        const int fl = t >> 3;          // frame sub-index (0..31)
        #pragma unroll
        for (int i = 0; i < 8; ++i) {
            const int f_local = fl + i * 32;
            const int tok = fmap[f_local];
            float4 v = make_float4(0.f, 0.f, 0.f, 0.f);
            if (tok >= 0)
                v = *(const float4*)&d[(size_t)tok * C_D + r0 + q * 4];
            ldo[q * 4 + 0][f_local] = v.x;
            ldo[q * 4 + 1][f_local] = v.y;
            ldo[q * 4 + 2][f_local] = v.z;
            ldo[q * 4 + 3][f_local] = v.w;
        }
        __syncthreads();
        const int lane4 = t & 63;       // frame group within row
        const int wid   = t >> 6;       // 0..3
        #pragma unroll
        for (int i = 0; i < 8; ++i) {
            const int row = i * 4 + wid;
            const float4 v = *(const float4*)&ldo[row][lane4 * 4];
            *(float4*)&out[(size_t)(r0 + row) * N_FRAMES + f0 + lane4 * 4] = v;
        }
    } else {
        // asr rows: out[640+r][f] = t_en[r][tok(f)] — row-contiguous gather.
        const int r0 = (rtile - N_RT_EN) * RT;
        const int lane4 = t & 63;
        const int wid   = t >> 6;
        #pragma unroll
        for (int i = 0; i < 8; ++i) {
            const int row = i * 4 + wid;
            const float* __restrict__ src = t_en + (size_t)(r0 + row) * L_TOK;
            const int fb = lane4 * 4;
            float4 v;
            const int t0 = fmap[fb + 0], t1 = fmap[fb + 1];
            const int t2 = fmap[fb + 2], t3 = fmap[fb + 3];
            v.x = (t0 < 0) ? 0.f : src[t0];
            v.y = (t1 < 0) ? 0.f : src[t1];
            v.z = (t2 < 0) ? 0.f : src[t2];
            v.w = (t3 < 0) ? 0.f : src[t3];
            *(float4*)&out[(size_t)(C_D + r0 + row) * N_FRAMES + f0 + fb] = v;
        }
    }
}

extern "C" void kernel_launch(void* const* d_in, const int* in_sizes, int n_in,
                              void* d_out, int out_size, void* d_ws, size_t ws_size,
                              hipStream_t stream) {
    const int*   pred_dur = (const int*)d_in[0];
    const float* d        = (const float*)d_in[1];
    const float* t_en     = (const float*)d_in[2];
    float* out = (float*)d_out;

    const int blocks = (N_RT_EN + N_RT_ASR) * N_FT;   // 36 * 32 = 1152
    fused_align_kernel<<<blocks, 256, 0, stream>>>(pred_dur, d, t_en, out);
}